// Round 8
// baseline (2066.573 us; speedup 1.0000x reference)
//
#include <hip/hip_runtime.h>
#include <math.h>

// BN(ch=T) -> LSTM(1->64) -> LSTM(64->64) -> FC+GELU.  B=262144 T=15 H=64.
// v8: v6 structure (register-resident B-fragments, persistent blocks) with
//     grid 768 / launch_bounds(256,3): v6's real usage (~128 VGPR + 32 AGPR
//     = 160 <= 512/3) already fits 3 waves/SIMD; v6 was grid-capped at 2.
//     Plus v_cvt_pk_bf16_f32 (1 instr) for the h bf16 stores.
//     (v7's LDS weight cache was mis-indexed -> NaN; reverted, unnecessary.)
//
// ws float offsets:
//   WS_SS    0     scale[15]@+0, shift[15]@+16
//   WS_B0    32    b_ih0+b_hh0 [256]
//   WS_B1    288   b_ih1+b_hh1 [256]
//   WS_FCT   1024  fcT[u][o] fp32 [64][64]
//   WS_STATS 5200  bn sums[15]@+0, sqsums[15]@+16
//   WS_BF    8192  bf16 B-fragments: 96 chunks x 64 lanes x 8 ushort (96 KB)
//     chunk<32:  L0 (w_hh0^T):  ks=chunk>>4 (K=64: 2), nt=chunk&15
//     chunk>=32: L1 ([w_ih1;w_hh1]^T): ks=(chunk-32)>>4 (K=128: 4), nt=&15
//     elem(lane,j) = B[k=32*ks+8*(lane>>4)+j][n=16*nt+(lane&15)]

typedef __attribute__((ext_vector_type(8))) short short8;
typedef __attribute__((ext_vector_type(4))) float f32x4;

namespace {
constexpr int kB = 262144;
constexpr int kT = 15;
constexpr int kTiles = kB / 32;   // 8192
constexpr int kGrid = 768;        // 3 blocks per CU
constexpr int WS_SS = 0;
constexpr int WS_B0 = 32;
constexpr int WS_B1 = 288;
constexpr int WS_FCT = 1024;
constexpr int WS_STATS = 5200;
constexpr int WS_BF = 8192;
}  // namespace

__device__ __forceinline__ float sigm(float x) {
  return __builtin_amdgcn_rcpf(1.f + __expf(-x));
}
__device__ __forceinline__ float tanhx(float x) {
  return 1.f - 2.f * __builtin_amdgcn_rcpf(1.f + __expf(2.f * x));
}
__device__ __forceinline__ ushort f2bf(float f) {
  unsigned u = __float_as_uint(f);
  unsigned r = (u + 0x7fffu + ((u >> 16) & 1u)) >> 16;  // RNE
  return (ushort)r;
}
// single-value bf16 convert via HW packed-cvt (RNE), 1 instr vs 4
__device__ __forceinline__ ushort f2bf_fast(float f) {
  unsigned r;
  asm("v_cvt_pk_bf16_f32 %0, %1, %2" : "=v"(r) : "v"(f), "v"(f));
  return (ushort)r;
}

__global__ void prep_kernel(const float* __restrict__ w_hh0,
                            const float* __restrict__ w_ih1,
                            const float* __restrict__ w_hh1,
                            const float* __restrict__ b_ih0,
                            const float* __restrict__ b_hh0,
                            const float* __restrict__ b_ih1,
                            const float* __restrict__ b_hh1,
                            const float* __restrict__ fc_w,
                            float* __restrict__ ws) {
  const int stride = gridDim.x * blockDim.x;
  const int t0 = blockIdx.x * blockDim.x + threadIdx.x;
  ushort* bf = (ushort*)(ws + WS_BF);
  for (int i = t0; i < 96 * 512; i += stride) {
    int chunk = i >> 9, lane = (i >> 3) & 63, j = i & 7;
    float v;
    if (chunk < 32) {
      int ks = chunk >> 4, nt = chunk & 15;
      int k = 32 * ks + 8 * (lane >> 4) + j;
      int n = 16 * nt + (lane & 15);
      v = w_hh0[n * 64 + k];
    } else {
      int c2 = chunk - 32;
      int ks = c2 >> 4, nt = c2 & 15;
      int k = 32 * ks + 8 * (lane >> 4) + j;
      int n = 16 * nt + (lane & 15);
      v = (k < 64) ? w_ih1[n * 64 + k] : w_hh1[n * 64 + (k - 64)];
    }
    bf[i] = f2bf(v);
  }
  for (int i = t0; i < 4096; i += stride) {
    int u = i >> 6, o = i & 63;
    ws[WS_FCT + i] = fc_w[o * 64 + u];
  }
  for (int i = t0; i < 256; i += stride) {
    ws[WS_B0 + i] = b_ih0[i] + b_hh0[i];
    ws[WS_B1 + i] = b_ih1[i] + b_hh1[i];
  }
  for (int i = t0; i < 32; i += stride) ws[WS_STATS + i] = 0.f;
}

// Each thread owns one chunk of 15 consecutive float4s (60 elems = 4 full
// mod-15 periods, chunk-aligned so t-indices are compile-time constants).
__global__ void bn_sums_kernel(const float* __restrict__ x,
                               float* __restrict__ ws) {
  __shared__ float ls[16], lq[16];
  const int tid = threadIdx.x;
  if (tid < 16) { ls[tid] = 0.f; lq[tid] = 0.f; }
  __syncthreads();
  const float4* x4 = (const float4*)x;
  const int c0 = (blockIdx.x * 256 + tid) * 15;
  float s[15], q[15];
#pragma unroll
  for (int t = 0; t < 15; ++t) { s[t] = 0.f; q[t] = 0.f; }
#pragma unroll
  for (int c = 0; c < 15; ++c) {
    float4 v = x4[c0 + c];
    s[(4 * c + 0) % 15] += v.x; q[(4 * c + 0) % 15] += v.x * v.x;
    s[(4 * c + 1) % 15] += v.y; q[(4 * c + 1) % 15] += v.y * v.y;
    s[(4 * c + 2) % 15] += v.z; q[(4 * c + 2) % 15] += v.z * v.z;
    s[(4 * c + 3) % 15] += v.w; q[(4 * c + 3) % 15] += v.w * v.w;
  }
#pragma unroll
  for (int t = 0; t < 15; ++t) {
    atomicAdd(&ls[t], s[t]);
    atomicAdd(&lq[t], q[t]);
  }
  __syncthreads();
  if (tid < 15) {
    atomicAdd(&ws[WS_STATS + tid], ls[tid]);
    atomicAdd(&ws[WS_STATS + 16 + tid], lq[tid]);
  }
}

__global__ void bn_final_kernel(const float* __restrict__ gamma,
                                const float* __restrict__ beta,
                                float* __restrict__ ws) {
  int t = threadIdx.x;
  if (t < 15) {
    const float inv = 1.f / (float)kB;
    float mean = ws[WS_STATS + t] * inv;
    float var = ws[WS_STATS + 16 + t] * inv - mean * mean;
    float sc = gamma[t] * rsqrtf(var + 1e-5f);
    ws[WS_SS + t] = sc;
    ws[WS_SS + 16 + t] = beta[t] - mean * sc;
  }
}

__global__ __launch_bounds__(256, 3) void lstm_fused_kernel(
    const float* __restrict__ x, const float* __restrict__ w_ih0,
    const float* __restrict__ fc_b, const float* __restrict__ ws,
    float* __restrict__ out) {
  __shared__ ushort hc[32 * 128];   // [row][unit] XOR-swizzled, 8 KB
  __shared__ float xsf[32 * 17];    // 2.2 KB
  __shared__ float h1f[32 * 68];    // fp32 h1 at t=14 for FC, 8.7 KB

  const int tid = threadIdx.x;
  const int lane = tid & 63;
  const int wv = tid >> 6;
  const int grp = lane >> 4;
  const int l15 = lane & 15;
  const int u = wv * 16 + l15;

  // ---- per-block one-time hoists ----
  float b0g[4], b1g[4], w0g[4];
#pragma unroll
  for (int j = 0; j < 4; ++j) {
    b0g[j] = ws[WS_B0 + u + 64 * j];
    b1g[j] = ws[WS_B1 + u + 64 * j];
    w0g[j] = w_ih0[u + 64 * j];
  }
  const short8* bfr = (const short8*)(ws + WS_BF);
  short8 bL0[8], bL1[16];
#pragma unroll
  for (int ks = 0; ks < 2; ++ks)
#pragma unroll
    for (int j = 0; j < 4; ++j)
      bL0[ks * 4 + j] = bfr[(ks * 16 + wv + 4 * j) * 64 + lane];
#pragma unroll
  for (int ks = 0; ks < 4; ++ks)
#pragma unroll
    for (int j = 0; j < 4; ++j)
      bL1[ks * 4 + j] = bfr[(32 + ks * 16 + wv + 4 * j) * 64 + lane];

  auto ldA = [&](int mt, int ks) -> short8 {
    int row = l15 + 16 * mt;
    int k0 = (32 * ks + 8 * grp) ^ ((row & 7) << 3);
    return *(const short8*)&hc[row * 128 + k0];
  };

#pragma unroll 1
  for (int tile = blockIdx.x; tile < kTiles; tile += kGrid) {
    const int bm0 = tile * 32;

    // stage x (BN folded) + zero h state.  Safe vs prior tile: all hc/xsf
    // reads ended >=1 barrier ago; h1f (FC input) is a separate buffer.
    for (int i = tid; i < 32 * kT; i += 256) {
      float v = x[(size_t)bm0 * kT + i];
      int m = i / 15, tt = i - m * 15;
      xsf[m * 17 + tt] = v * ws[WS_SS + tt] + ws[WS_SS + 16 + tt];
    }
    for (int i = tid; i < 2048; i += 256) ((unsigned*)hc)[i] = 0u;

    float c0r[8], c1r[8];
#pragma unroll
    for (int i = 0; i < 8; ++i) { c0r[i] = 0.f; c1r[i] = 0.f; }

    __syncthreads();

#pragma unroll 1
    for (int t = 0; t < kT; ++t) {
      // ---------------- layer 0 ----------------
      f32x4 acc[2][4];
#pragma unroll
      for (int mt = 0; mt < 2; ++mt)
#pragma unroll
        for (int r = 0; r < 4; ++r) {
          float xv = xsf[(16 * mt + 4 * grp + r) * 17 + t];
#pragma unroll
          for (int j = 0; j < 4; ++j) acc[mt][j][r] = fmaf(xv, w0g[j], b0g[j]);
        }
#pragma unroll
      for (int ks = 0; ks < 2; ++ks) {
        short8 a0 = ldA(0, ks);
        short8 a1 = ldA(1, ks);
#pragma unroll
        for (int j = 0; j < 4; ++j) {
          acc[0][j] = __builtin_amdgcn_mfma_f32_16x16x32_bf16(a0, bL0[ks * 4 + j], acc[0][j], 0, 0, 0);
          acc[1][j] = __builtin_amdgcn_mfma_f32_16x16x32_bf16(a1, bL0[ks * 4 + j], acc[1][j], 0, 0, 0);
        }
      }
      __syncthreads();  // L0 A-reads done before h0_t overwrite
#pragma unroll
      for (int mt = 0; mt < 2; ++mt)
#pragma unroll
        for (int r = 0; r < 4; ++r) {
          int row = 16 * mt + 4 * grp + r;
          float zi = acc[mt][0][r], zf = acc[mt][1][r];
          float zg = acc[mt][2][r], zo = acc[mt][3][r];
          float ig = sigm(zi), fg = sigm(zf), gg = tanhx(zg), og = sigm(zo);
          float c = fmaf(fg, c0r[mt * 4 + r], ig * gg);
          c0r[mt * 4 + r] = c;
          float h = og * tanhx(c);
          hc[row * 128 + (u ^ ((row & 7) << 3))] = f2bf_fast(h);
        }
      __syncthreads();  // h0_t visible (also orders prev-iter h1_t writes)

      // ---------------- layer 1 ----------------
#pragma unroll
      for (int mt = 0; mt < 2; ++mt)
#pragma unroll
        for (int j = 0; j < 4; ++j)
#pragma unroll
          for (int r = 0; r < 4; ++r) acc[mt][j][r] = b1g[j];
#pragma unroll
      for (int ks = 0; ks < 4; ++ks) {
        short8 a0 = ldA(0, ks);
        short8 a1 = ldA(1, ks);
#pragma unroll
        for (int j = 0; j < 4; ++j) {
          acc[0][j] = __builtin_amdgcn_mfma_f32_16x16x32_bf16(a0, bL1[ks * 4 + j], acc[0][j], 0, 0, 0);
          acc[1][j] = __builtin_amdgcn_mfma_f32_16x16x32_bf16(a1, bL1[ks * 4 + j], acc[1][j], 0, 0, 0);
        }
      }
      __syncthreads();  // L1 A-reads done before h1_t overwrite
#pragma unroll
      for (int mt = 0; mt < 2; ++mt)
#pragma unroll
        for (int r = 0; r < 4; ++r) {
          int row = 16 * mt + 4 * grp + r;
          float zi = acc[mt][0][r], zf = acc[mt][1][r];
          float zg = acc[mt][2][r], zo = acc[mt][3][r];
          float ig = sigm(zi), fg = sigm(zf), gg = tanhx(zg), og = sigm(zo);
          float c = fmaf(fg, c1r[mt * 4 + r], ig * gg);
          c1r[mt * 4 + r] = c;
          float h = og * tanhx(c);
          if (t < kT - 1) {
            hc[row * 128 + ((64 + u) ^ ((row & 7) << 3))] = f2bf_fast(h);
          } else {
            h1f[row * 68 + u] = h;
          }
        }
      // no barrier: next L0 reads only h0 cols; h1 ordered by next bar2.
    }
    __syncthreads();  // h1f visible for FC

    // ---------------- FC + exact-erf GELU (fp32) ----------------
    {
      const int o = tid & 63;
      const int ms = tid >> 6;
      float yv[8];
      float fb = fc_b[o];
#pragma unroll
      for (int i = 0; i < 8; ++i) yv[i] = fb;
#pragma unroll 1
      for (int u0 = 0; u0 < 64; u0 += 4) {
        float q0 = ws[WS_FCT + (u0 + 0) * 64 + o];
        float q1 = ws[WS_FCT + (u0 + 1) * 64 + o];
        float q2 = ws[WS_FCT + (u0 + 2) * 64 + o];
        float q3 = ws[WS_FCT + (u0 + 3) * 64 + o];
#pragma unroll
        for (int i = 0; i < 8; ++i) {
          const float4 hq = *(const float4*)&h1f[(ms * 8 + i) * 68 + u0];
          yv[i] = fmaf(hq.x, q0, yv[i]);
          yv[i] = fmaf(hq.y, q1, yv[i]);
          yv[i] = fmaf(hq.z, q2, yv[i]);
          yv[i] = fmaf(hq.w, q3, yv[i]);
        }
      }
#pragma unroll
      for (int i = 0; i < 8; ++i) {
        float v = yv[i];
        float g = 0.5f * v * (1.f + erff(v * 0.70710678118654752f));
        out[(size_t)(bm0 + ms * 8 + i) * 64 + o] = g;
      }
    }
    // no barrier: next tile's hc/xsf writes don't touch h1f/out, and all
    // waves' hc/xsf reads for this tile ended before the barrier above.
  }
}

extern "C" void kernel_launch(void* const* d_in, const int* in_sizes, int n_in,
                              void* d_out, int out_size, void* d_ws, size_t ws_size,
                              hipStream_t stream) {
  const float* x = (const float*)d_in[0];
  const float* bn_gamma = (const float*)d_in[1];
  const float* bn_beta = (const float*)d_in[2];
  const float* w_ih0 = (const float*)d_in[3];
  const float* w_hh0 = (const float*)d_in[4];
  const float* b_ih0 = (const float*)d_in[5];
  const float* b_hh0 = (const float*)d_in[6];
  const float* w_ih1 = (const float*)d_in[7];
  const float* w_hh1 = (const float*)d_in[8];
  const float* b_ih1 = (const float*)d_in[9];
  const float* b_hh1 = (const float*)d_in[10];
  const float* fc_w = (const float*)d_in[11];
  const float* fc_b = (const float*)d_in[12];
  float* ws = (float*)d_ws;
  float* out = (float*)d_out;

  hipLaunchKernelGGL(prep_kernel, dim3(64), dim3(256), 0, stream,
                     w_hh0, w_ih1, w_hh1, b_ih0, b_hh0, b_ih1, b_hh1, fc_w, ws);
  hipLaunchKernelGGL(bn_sums_kernel, dim3(256), dim3(256), 0, stream, x, ws);
  hipLaunchKernelGGL(bn_final_kernel, dim3(1), dim3(64), 0, stream,
                     bn_gamma, bn_beta, ws);
  hipLaunchKernelGGL(lstm_fused_kernel, dim3(kGrid), dim3(256), 0, stream,
                     x, w_ih0, fc_b, ws, out);
}

// Round 9
// 1539.033 us; speedup vs baseline: 1.3428x; 1.3428x over previous
//
#include <hip/hip_runtime.h>
#include <math.h>

// BN(ch=T) -> LSTM(1->64) -> LSTM(64->64) -> FC+GELU.  B=262144 T=15 H=64.
// v9: v7's plan, correctly: L1 ks2,3 B-fragments in LDS (32 KB, staged once
//     per block; stride-1 conflict-free reads), register demand ~160 -> real
//     3 blocks/CU at launch_bounds(256,3). h1f aliased onto hc+xsf (dead by
//     then) so LDS/block = 43 KB. v8 lesson: 96 frag regs + 3 waves/SIMD is
//     infeasible -> compiler dropped frags to global re-loads (5 GB FETCH).
//
// ws float offsets:
//   WS_SS    0     scale[15]@+0, shift[15]@+16
//   WS_B0    32    b_ih0+b_hh0 [256]
//   WS_B1    288   b_ih1+b_hh1 [256]
//   WS_FCT   1024  fcT[u][o] fp32 [64][64]
//   WS_STATS 5200  bn sums[15]@+0, sqsums[15]@+16
//   WS_BF    8192  bf16 B-fragments: 96 chunks x 64 lanes x 8 ushort (96 KB)
//     chunk<32:  L0 (w_hh0^T):  ks=chunk>>4 (K=64: 2), nt=chunk&15
//     chunk>=32: L1 ([w_ih1;w_hh1]^T): ks=(chunk-32)>>4 (K=128: 4), nt=&15
//     elem(lane,j) = B[k=32*ks+8*(lane>>4)+j][n=16*nt+(lane&15)]

typedef __attribute__((ext_vector_type(8))) short short8;
typedef __attribute__((ext_vector_type(4))) float f32x4;

namespace {
constexpr int kB = 262144;
constexpr int kT = 15;
constexpr int kTiles = kB / 32;   // 8192
constexpr int kGrid = 768;        // 3 blocks per CU
constexpr int WS_SS = 0;
constexpr int WS_B0 = 32;
constexpr int WS_B1 = 288;
constexpr int WS_FCT = 1024;
constexpr int WS_STATS = 5200;
constexpr int WS_BF = 8192;
}  // namespace

__device__ __forceinline__ float sigm(float x) {
  return __builtin_amdgcn_rcpf(1.f + __expf(-x));
}
__device__ __forceinline__ float tanhx(float x) {
  return 1.f - 2.f * __builtin_amdgcn_rcpf(1.f + __expf(2.f * x));
}
__device__ __forceinline__ ushort f2bf(float f) {
  unsigned u = __float_as_uint(f);
  unsigned r = (u + 0x7fffu + ((u >> 16) & 1u)) >> 16;  // RNE
  return (ushort)r;
}
// single-value bf16 convert via HW packed-cvt (RNE), 1 instr vs 4
__device__ __forceinline__ ushort f2bf_fast(float f) {
  unsigned r;
  asm("v_cvt_pk_bf16_f32 %0, %1, %2" : "=v"(r) : "v"(f), "v"(f));
  return (ushort)r;
}

__global__ void prep_kernel(const float* __restrict__ w_hh0,
                            const float* __restrict__ w_ih1,
                            const float* __restrict__ w_hh1,
                            const float* __restrict__ b_ih0,
                            const float* __restrict__ b_hh0,
                            const float* __restrict__ b_ih1,
                            const float* __restrict__ b_hh1,
                            const float* __restrict__ fc_w,
                            float* __restrict__ ws) {
  const int stride = gridDim.x * blockDim.x;
  const int t0 = blockIdx.x * blockDim.x + threadIdx.x;
  ushort* bf = (ushort*)(ws + WS_BF);
  for (int i = t0; i < 96 * 512; i += stride) {
    int chunk = i >> 9, lane = (i >> 3) & 63, j = i & 7;
    float v;
    if (chunk < 32) {
      int ks = chunk >> 4, nt = chunk & 15;
      int k = 32 * ks + 8 * (lane >> 4) + j;
      int n = 16 * nt + (lane & 15);
      v = w_hh0[n * 64 + k];
    } else {
      int c2 = chunk - 32;
      int ks = c2 >> 4, nt = c2 & 15;
      int k = 32 * ks + 8 * (lane >> 4) + j;
      int n = 16 * nt + (lane & 15);
      v = (k < 64) ? w_ih1[n * 64 + k] : w_hh1[n * 64 + (k - 64)];
    }
    bf[i] = f2bf(v);
  }
  for (int i = t0; i < 4096; i += stride) {
    int u = i >> 6, o = i & 63;
    ws[WS_FCT + i] = fc_w[o * 64 + u];
  }
  for (int i = t0; i < 256; i += stride) {
    ws[WS_B0 + i] = b_ih0[i] + b_hh0[i];
    ws[WS_B1 + i] = b_ih1[i] + b_hh1[i];
  }
  for (int i = t0; i < 32; i += stride) ws[WS_STATS + i] = 0.f;
}

// Each thread owns one chunk of 15 consecutive float4s (60 elems = 4 full
// mod-15 periods, chunk-aligned so t-indices are compile-time constants).
__global__ void bn_sums_kernel(const float* __restrict__ x,
                               float* __restrict__ ws) {
  __shared__ float ls[16], lq[16];
  const int tid = threadIdx.x;
  if (tid < 16) { ls[tid] = 0.f; lq[tid] = 0.f; }
  __syncthreads();
  const float4* x4 = (const float4*)x;
  const int c0 = (blockIdx.x * 256 + tid) * 15;
  float s[15], q[15];
#pragma unroll
  for (int t = 0; t < 15; ++t) { s[t] = 0.f; q[t] = 0.f; }
#pragma unroll
  for (int c = 0; c < 15; ++c) {
    float4 v = x4[c0 + c];
    s[(4 * c + 0) % 15] += v.x; q[(4 * c + 0) % 15] += v.x * v.x;
    s[(4 * c + 1) % 15] += v.y; q[(4 * c + 1) % 15] += v.y * v.y;
    s[(4 * c + 2) % 15] += v.z; q[(4 * c + 2) % 15] += v.z * v.z;
    s[(4 * c + 3) % 15] += v.w; q[(4 * c + 3) % 15] += v.w * v.w;
  }
#pragma unroll
  for (int t = 0; t < 15; ++t) {
    atomicAdd(&ls[t], s[t]);
    atomicAdd(&lq[t], q[t]);
  }
  __syncthreads();
  if (tid < 15) {
    atomicAdd(&ws[WS_STATS + tid], ls[tid]);
    atomicAdd(&ws[WS_STATS + 16 + tid], lq[tid]);
  }
}

__global__ void bn_final_kernel(const float* __restrict__ gamma,
                                const float* __restrict__ beta,
                                float* __restrict__ ws) {
  int t = threadIdx.x;
  if (t < 15) {
    const float inv = 1.f / (float)kB;
    float mean = ws[WS_STATS + t] * inv;
    float var = ws[WS_STATS + 16 + t] * inv - mean * mean;
    float sc = gamma[t] * rsqrtf(var + 1e-5f);
    ws[WS_SS + t] = sc;
    ws[WS_SS + 16 + t] = beta[t] - mean * sc;
  }
}

// smem layout (bytes):
//   [0, 32768)      wlds: L1 ks2,3 frag chunks 64..95 (32 x 1 KB)
//   [32768, 40960)  hc ushort[32][128] XOR-swizzled
//   [40960, 43136)  xsf float[32][17]
//   h1f float[32][68] aliases [32768, 41472) -- hc+xsf dead when written
__global__ __launch_bounds__(256, 3) void lstm_fused_kernel(
    const float* __restrict__ x, const float* __restrict__ w_ih0,
    const float* __restrict__ fc_b, const float* __restrict__ ws,
    float* __restrict__ out) {
  __shared__ __align__(16) char smem[43136];
  ushort* wlds = (ushort*)smem;
  ushort* hc = (ushort*)(smem + 32768);
  float* xsf = (float*)(smem + 40960);
  float* h1f = (float*)(smem + 32768);

  const int tid = threadIdx.x;
  const int lane = tid & 63;
  const int wv = tid >> 6;
  const int grp = lane >> 4;
  const int l15 = lane & 15;
  const int u = wv * 16 + l15;

  // ---- per-block one-time hoists ----
  float b0g[4], b1g[4], w0g[4];
#pragma unroll
  for (int j = 0; j < 4; ++j) {
    b0g[j] = ws[WS_B0 + u + 64 * j];
    b1g[j] = ws[WS_B1 + u + 64 * j];
    w0g[j] = w_ih0[u + 64 * j];
  }
  const short8* bfr = (const short8*)(ws + WS_BF);
  short8 bL0[8], bL1[8];  // regs: L0 ks0,1 + L1 ks0,1.  L1 ks2,3 in LDS.
#pragma unroll
  for (int ks = 0; ks < 2; ++ks)
#pragma unroll
    for (int j = 0; j < 4; ++j)
      bL0[ks * 4 + j] = bfr[(ks * 16 + wv + 4 * j) * 64 + lane];
#pragma unroll
  for (int ks = 0; ks < 2; ++ks)
#pragma unroll
    for (int j = 0; j < 4; ++j)
      bL1[ks * 4 + j] = bfr[(32 + ks * 16 + wv + 4 * j) * 64 + lane];
  // stage frag chunks 64..95 (L1 ks2,3) into LDS: 32 KB = 2048 uint4
  {
    const uint4* src = (const uint4*)((const ushort*)(ws + WS_BF) + 64 * 512);
    uint4* dst = (uint4*)wlds;
    for (int i = tid; i < 2048; i += 256) dst[i] = src[i];
  }

  auto ldA = [&](int mt, int ks) -> short8 {
    int row = l15 + 16 * mt;
    int k0 = (32 * ks + 8 * grp) ^ ((row & 7) << 3);
    return *(const short8*)&hc[row * 128 + k0];
  };
  auto ldW = [&](int ks, int j) -> short8 {  // ks in {2,3}; chunk 64+cl
    int cl = (ks - 2) * 16 + wv + 4 * j;
    return *(const short8*)&wlds[cl * 512 + lane * 8];
  };

#pragma unroll 1
  for (int tile = blockIdx.x; tile < kTiles; tile += kGrid) {
    const int bm0 = tile * 32;

    // stage x (BN folded) + zero h state.  (barrier at end of prev tile's
    // FC protects the h1f alias; wlds staging covered by first tile barrier)
    for (int i = tid; i < 32 * kT; i += 256) {
      float v = x[(size_t)bm0 * kT + i];
      int m = i / 15, tt = i - m * 15;
      xsf[m * 17 + tt] = v * ws[WS_SS + tt] + ws[WS_SS + 16 + tt];
    }
    for (int i = tid; i < 2048; i += 256) ((unsigned*)hc)[i] = 0u;

    float c0r[8], c1r[8];
#pragma unroll
    for (int i = 0; i < 8; ++i) { c0r[i] = 0.f; c1r[i] = 0.f; }

    __syncthreads();

#pragma unroll 1
    for (int t = 0; t < kT; ++t) {
      // ---------------- layer 0 ----------------
      f32x4 acc[2][4];
#pragma unroll
      for (int mt = 0; mt < 2; ++mt)
#pragma unroll
        for (int r = 0; r < 4; ++r) {
          float xv = xsf[(16 * mt + 4 * grp + r) * 17 + t];
#pragma unroll
          for (int j = 0; j < 4; ++j) acc[mt][j][r] = fmaf(xv, w0g[j], b0g[j]);
        }
#pragma unroll
      for (int ks = 0; ks < 2; ++ks) {
        short8 a0 = ldA(0, ks);
        short8 a1 = ldA(1, ks);
#pragma unroll
        for (int j = 0; j < 4; ++j) {
          acc[0][j] = __builtin_amdgcn_mfma_f32_16x16x32_bf16(a0, bL0[ks * 4 + j], acc[0][j], 0, 0, 0);
          acc[1][j] = __builtin_amdgcn_mfma_f32_16x16x32_bf16(a1, bL0[ks * 4 + j], acc[1][j], 0, 0, 0);
        }
      }
      __syncthreads();  // L0 A-reads done before h0_t overwrite
#pragma unroll
      for (int mt = 0; mt < 2; ++mt)
#pragma unroll
        for (int r = 0; r < 4; ++r) {
          int row = 16 * mt + 4 * grp + r;
          float zi = acc[mt][0][r], zf = acc[mt][1][r];
          float zg = acc[mt][2][r], zo = acc[mt][3][r];
          float ig = sigm(zi), fg = sigm(zf), gg = tanhx(zg), og = sigm(zo);
          float c = fmaf(fg, c0r[mt * 4 + r], ig * gg);
          c0r[mt * 4 + r] = c;
          float h = og * tanhx(c);
          hc[row * 128 + (u ^ ((row & 7) << 3))] = f2bf_fast(h);
        }
      __syncthreads();  // h0_t visible (also orders prev-iter h1_t writes)

      // ---------------- layer 1 ----------------
#pragma unroll
      for (int mt = 0; mt < 2; ++mt)
#pragma unroll
        for (int j = 0; j < 4; ++j)
#pragma unroll
          for (int r = 0; r < 4; ++r) acc[mt][j][r] = b1g[j];
#pragma unroll
      for (int ks = 0; ks < 2; ++ks) {
        short8 a0 = ldA(0, ks);
        short8 a1 = ldA(1, ks);
#pragma unroll
        for (int j = 0; j < 4; ++j) {
          acc[0][j] = __builtin_amdgcn_mfma_f32_16x16x32_bf16(a0, bL1[ks * 4 + j], acc[0][j], 0, 0, 0);
          acc[1][j] = __builtin_amdgcn_mfma_f32_16x16x32_bf16(a1, bL1[ks * 4 + j], acc[1][j], 0, 0, 0);
        }
      }
#pragma unroll
      for (int ks = 2; ks < 4; ++ks) {
        short8 a0 = ldA(0, ks);
        short8 a1 = ldA(1, ks);
#pragma unroll
        for (int j = 0; j < 4; ++j) {
          short8 bb = ldW(ks, j);
          acc[0][j] = __builtin_amdgcn_mfma_f32_16x16x32_bf16(a0, bb, acc[0][j], 0, 0, 0);
          acc[1][j] = __builtin_amdgcn_mfma_f32_16x16x32_bf16(a1, bb, acc[1][j], 0, 0, 0);
        }
      }
      __syncthreads();  // L1 A-reads done before h1_t / h1f-alias overwrite
#pragma unroll
      for (int mt = 0; mt < 2; ++mt)
#pragma unroll
        for (int r = 0; r < 4; ++r) {
          int row = 16 * mt + 4 * grp + r;
          float zi = acc[mt][0][r], zf = acc[mt][1][r];
          float zg = acc[mt][2][r], zo = acc[mt][3][r];
          float ig = sigm(zi), fg = sigm(zf), gg = tanhx(zg), og = sigm(zo);
          float c = fmaf(fg, c1r[mt * 4 + r], ig * gg);
          c1r[mt * 4 + r] = c;
          float h = og * tanhx(c);
          if (t < kT - 1) {
            hc[row * 128 + ((64 + u) ^ ((row & 7) << 3))] = f2bf_fast(h);
          } else {
            h1f[row * 68 + u] = h;  // aliases hc+xsf; both dead at t=14 here
          }
        }
      // no barrier: next L0 reads only h0 cols; h1 ordered by next bar2.
    }
    __syncthreads();  // h1f visible for FC

    // ---------------- FC + exact-erf GELU (fp32) ----------------
    {
      const int o = tid & 63;
      const int ms = tid >> 6;
      float yv[8];
      float fb = fc_b[o];
#pragma unroll
      for (int i = 0; i < 8; ++i) yv[i] = fb;
#pragma unroll 1
      for (int u0 = 0; u0 < 64; u0 += 4) {
        float q0 = ws[WS_FCT + (u0 + 0) * 64 + o];
        float q1 = ws[WS_FCT + (u0 + 1) * 64 + o];
        float q2 = ws[WS_FCT + (u0 + 2) * 64 + o];
        float q3 = ws[WS_FCT + (u0 + 3) * 64 + o];
#pragma unroll
        for (int i = 0; i < 8; ++i) {
          const float4 hq = *(const float4*)&h1f[(ms * 8 + i) * 68 + u0];
          yv[i] = fmaf(hq.x, q0, yv[i]);
          yv[i] = fmaf(hq.y, q1, yv[i]);
          yv[i] = fmaf(hq.z, q2, yv[i]);
          yv[i] = fmaf(hq.w, q3, yv[i]);
        }
      }
#pragma unroll
      for (int i = 0; i < 8; ++i) {
        float v = yv[i];
        float g = 0.5f * v * (1.f + erff(v * 0.70710678118654752f));
        out[(size_t)(bm0 + ms * 8 + i) * 64 + o] = g;
      }
    }
    __syncthreads();  // h1f reads done before next tile's hc/xsf staging
  }
}

extern "C" void kernel_launch(void* const* d_in, const int* in_sizes, int n_in,
                              void* d_out, int out_size, void* d_ws, size_t ws_size,
                              hipStream_t stream) {
  const float* x = (const float*)d_in[0];
  const float* bn_gamma = (const float*)d_in[1];
  const float* bn_beta = (const float*)d_in[2];
  const float* w_ih0 = (const float*)d_in[3];
  const float* w_hh0 = (const float*)d_in[4];
  const float* b_ih0 = (const float*)d_in[5];
  const float* b_hh0 = (const float*)d_in[6];
  const float* w_ih1 = (const float*)d_in[7];
  const float* w_hh1 = (const float*)d_in[8];
  const float* b_ih1 = (const float*)d_in[9];
  const float* b_hh1 = (const float*)d_in[10];
  const float* fc_w = (const float*)d_in[11];
  const float* fc_b = (const float*)d_in[12];
  float* ws = (float*)d_ws;
  float* out = (float*)d_out;

  hipLaunchKernelGGL(prep_kernel, dim3(64), dim3(256), 0, stream,
                     w_hh0, w_ih1, w_hh1, b_ih0, b_hh0, b_ih1, b_hh1, fc_w, ws);
  hipLaunchKernelGGL(bn_sums_kernel, dim3(256), dim3(256), 0, stream, x, ws);
  hipLaunchKernelGGL(bn_final_kernel, dim3(1), dim3(64), 0, stream,
                     bn_gamma, bn_beta, ws);
  hipLaunchKernelGGL(lstm_fused_kernel, dim3(kGrid), dim3(256), 0, stream,
                     x, w_ih0, fc_b, ws, out);
}

// Round 11
// 813.755 us; speedup vs baseline: 2.5396x; 1.8913x over previous
//
#include <hip/hip_runtime.h>
#include <math.h>

// BN(ch=T) -> LSTM(1->64) -> LSTM(64->64) -> FC+GELU.  B=262144 T=15 H=64.
// v11: v10 with the exp2 trans-use hazard fixed. v10's raw `asm(v_exp_f32)`
//      hid the transcendental from LLVM's hazard recognizer -> consumer in
//      the hazard slot -> corrupted gates (absmax 2.39). Builtin (or asm with
//      baked s_nop) restores correctness. Structure unchanged from v10:
//  - h0/h1 double-buffered by t-parity -> 1 barrier per t (vs 3 in v6)
//  - exp2-domain weights (i/f/o cols scaled by -log2e, g by +2log2e in prep)
//  - v_cvt_pk_bf16_f32 for h->bf16 stores
//
// ws float offsets:
//   WS_SS    0     scale[15]@+0, shift[15]@+16
//   WS_B0    32    scaled b_ih0+b_hh0 [256]
//   WS_B1    288   scaled b_ih1+b_hh1 [256]
//   WS_FCT   1024  fcT[u][o] fp32 [64][64]  (unscaled)
//   WS_STATS 5200  bn sums[15]@+0, sqsums[15]@+16
//   WS_BF    8192  bf16 B-fragments (gate-scaled): 96 chunks x 512 ushort
//     chunk<32:  L0 (w_hh0^T):  ks=chunk>>4 (K=64: 2), nt=chunk&15
//     chunk>=32: L1 ([w_ih1;w_hh1]^T): ks=(chunk-32)>>4 (K=128: 4), nt=&15
//     elem(lane,j) = B[k=32*ks+8*(lane>>4)+j][n=16*nt+(lane&15)]

typedef __attribute__((ext_vector_type(8))) short short8;
typedef __attribute__((ext_vector_type(4))) float f32x4;

namespace {
constexpr int kB = 262144;
constexpr int kT = 15;
constexpr int kTiles = kB / 32;   // 8192
constexpr int kGrid = 512;        // 2 blocks per CU (proven allocator regime)
constexpr int WS_SS = 0;
constexpr int WS_B0 = 32;
constexpr int WS_B1 = 288;
constexpr int WS_FCT = 1024;
constexpr int WS_STATS = 5200;
constexpr int WS_BF = 8192;
}  // namespace

// v_exp_f32 computes 2^x. MUST go through the builtin (or carry an explicit
// hazard guard): trans-op results need a wait state before the next VALU
// consumer, and the compiler only inserts it for instructions it can see.
#if __has_builtin(__builtin_amdgcn_exp2f)
__device__ __forceinline__ float exp2x(float x) {
  return __builtin_amdgcn_exp2f(x);
}
#else
__device__ __forceinline__ float exp2x(float x) {
  float r;
  asm("v_exp_f32 %0, %1\n\ts_nop 1" : "=v"(r) : "v"(x));
  return r;
}
#endif

__device__ __forceinline__ ushort f2bf(float f) {
  unsigned u = __float_as_uint(f);
  unsigned r = (u + 0x7fffu + ((u >> 16) & 1u)) >> 16;  // RNE
  return (ushort)r;
}
__device__ __forceinline__ ushort f2bf_fast(float f) {
  unsigned r;
  asm("v_cvt_pk_bf16_f32 %0, %1, %2" : "=v"(r) : "v"(f), "v"(f));
  return (ushort)r;
}
// gate scale for gate index g (0=i,1=f,2=g,3=o): sigmoid gates get -log2e
// (folds exp(-z) negation), tanh gate gets +2log2e (tanh(x)=1-2/(1+e^{2x}))
__device__ __forceinline__ float gscale(int g) {
  return (g == 2) ? 2.88539008177792681472f : -1.44269504088896340736f;
}

__global__ void prep_kernel(const float* __restrict__ w_hh0,
                            const float* __restrict__ w_ih1,
                            const float* __restrict__ w_hh1,
                            const float* __restrict__ b_ih0,
                            const float* __restrict__ b_hh0,
                            const float* __restrict__ b_ih1,
                            const float* __restrict__ b_hh1,
                            const float* __restrict__ fc_w,
                            float* __restrict__ ws) {
  const int stride = gridDim.x * blockDim.x;
  const int t0 = blockIdx.x * blockDim.x + threadIdx.x;
  ushort* bf = (ushort*)(ws + WS_BF);
  for (int i = t0; i < 96 * 512; i += stride) {
    int chunk = i >> 9, lane = (i >> 3) & 63, j = i & 7;
    float v;
    int n;
    if (chunk < 32) {
      int ks = chunk >> 4, nt = chunk & 15;
      int k = 32 * ks + 8 * (lane >> 4) + j;
      n = 16 * nt + (lane & 15);
      v = w_hh0[n * 64 + k];
    } else {
      int c2 = chunk - 32;
      int ks = c2 >> 4, nt = c2 & 15;
      int k = 32 * ks + 8 * (lane >> 4) + j;
      n = 16 * nt + (lane & 15);
      v = (k < 64) ? w_ih1[n * 64 + k] : w_hh1[n * 64 + (k - 64)];
    }
    bf[i] = f2bf(v * gscale(n >> 6));
  }
  for (int i = t0; i < 4096; i += stride) {
    int u = i >> 6, o = i & 63;
    ws[WS_FCT + i] = fc_w[o * 64 + u];
  }
  for (int i = t0; i < 256; i += stride) {
    float sc = gscale(i >> 6);
    ws[WS_B0 + i] = (b_ih0[i] + b_hh0[i]) * sc;
    ws[WS_B1 + i] = (b_ih1[i] + b_hh1[i]) * sc;
  }
  for (int i = t0; i < 32; i += stride) ws[WS_STATS + i] = 0.f;
}

// Each thread owns one chunk of 15 consecutive float4s (60 elems = 4 full
// mod-15 periods, chunk-aligned so t-indices are compile-time constants).
__global__ void bn_sums_kernel(const float* __restrict__ x,
                               float* __restrict__ ws) {
  __shared__ float ls[16], lq[16];
  const int tid = threadIdx.x;
  if (tid < 16) { ls[tid] = 0.f; lq[tid] = 0.f; }
  __syncthreads();
  const float4* x4 = (const float4*)x;
  const int c0 = (blockIdx.x * 256 + tid) * 15;
  float s[15], q[15];
#pragma unroll
  for (int t = 0; t < 15; ++t) { s[t] = 0.f; q[t] = 0.f; }
#pragma unroll
  for (int c = 0; c < 15; ++c) {
    float4 v = x4[c0 + c];
    s[(4 * c + 0) % 15] += v.x; q[(4 * c + 0) % 15] += v.x * v.x;
    s[(4 * c + 1) % 15] += v.y; q[(4 * c + 1) % 15] += v.y * v.y;
    s[(4 * c + 2) % 15] += v.z; q[(4 * c + 2) % 15] += v.z * v.z;
    s[(4 * c + 3) % 15] += v.w; q[(4 * c + 3) % 15] += v.w * v.w;
  }
#pragma unroll
  for (int t = 0; t < 15; ++t) {
    atomicAdd(&ls[t], s[t]);
    atomicAdd(&lq[t], q[t]);
  }
  __syncthreads();
  if (tid < 15) {
    atomicAdd(&ws[WS_STATS + tid], ls[tid]);
    atomicAdd(&ws[WS_STATS + 16 + tid], lq[tid]);
  }
}

__global__ void bn_final_kernel(const float* __restrict__ gamma,
                                const float* __restrict__ beta,
                                float* __restrict__ ws) {
  int t = threadIdx.x;
  if (t < 15) {
    const float inv = 1.f / (float)kB;
    float mean = ws[WS_STATS + t] * inv;
    float var = ws[WS_STATS + 16 + t] * inv - mean * mean;
    float sc = gamma[t] * rsqrtf(var + 1e-5f);
    ws[WS_SS + t] = sc;
    ws[WS_SS + 16 + t] = beta[t] - mean * sc;
  }
}

__global__ __launch_bounds__(256, 2) void lstm_fused_kernel(
    const float* __restrict__ x, const float* __restrict__ w_ih0,
    const float* __restrict__ fc_b, const float* __restrict__ ws,
    float* __restrict__ out) {
  // h0b/h1b: [parity][row][unit] ushort, XOR-swizzled rows (64-ushort rows)
  __shared__ ushort h0b[2][32 * 64];   // 8 KB
  __shared__ ushort h1b[2][32 * 64];   // 8 KB
  __shared__ float xsf[32 * 17];       // 2.2 KB
  __shared__ float h1f[32 * 68];       // 8.7 KB

  const int tid = threadIdx.x;
  const int lane = tid & 63;
  const int wv = tid >> 6;
  const int grp = lane >> 4;
  const int l15 = lane & 15;
  const int u = wv * 16 + l15;

  // ---- per-block one-time hoists (identical shape to v6: allocator-proven) ----
  float b0g[4], b1g[4], w0g[4];
#pragma unroll
  for (int j = 0; j < 4; ++j) {
    b0g[j] = ws[WS_B0 + u + 64 * j];
    b1g[j] = ws[WS_B1 + u + 64 * j];
    w0g[j] = w_ih0[u + 64 * j] * gscale(j);
  }
  const short8* bfr = (const short8*)(ws + WS_BF);
  short8 bL0[8], bL1[16];
#pragma unroll
  for (int ks = 0; ks < 2; ++ks)
#pragma unroll
    for (int j = 0; j < 4; ++j)
      bL0[ks * 4 + j] = bfr[(ks * 16 + wv + 4 * j) * 64 + lane];
#pragma unroll
  for (int ks = 0; ks < 4; ++ks)
#pragma unroll
    for (int j = 0; j < 4; ++j)
      bL1[ks * 4 + j] = bfr[(32 + ks * 16 + wv + 4 * j) * 64 + lane];

  // A-fragment read: rows 0..15 (+16*mt), k-slice base kbase+8*grp, XOR swz
  auto ldA = [&](const ushort* buf, int mt, int kbase) -> short8 {
    int row = l15 + 16 * mt;
    int off = (kbase + 8 * grp) ^ ((row & 7) << 3);
    return *(const short8*)&buf[row * 64 + off];
  };

#pragma unroll 1
  for (int tile = blockIdx.x; tile < kTiles; tile += kGrid) {
    const int bm0 = tile * 32;

    // stage x (BN folded) + zero parity-1 h buffers (t=0 reads parity 1).
    for (int i = tid; i < 32 * kT; i += 256) {
      float v = x[(size_t)bm0 * kT + i];
      int m = i / 15, tt = i - m * 15;
      xsf[m * 17 + tt] = v * ws[WS_SS + tt] + ws[WS_SS + 16 + tt];
    }
    for (int i = tid; i < 1024; i += 256) {
      ((unsigned*)h0b[1])[i] = 0u;
      ((unsigned*)h1b[1])[i] = 0u;
    }

    float c0r[8], c1r[8];
#pragma unroll
    for (int i = 0; i < 8; ++i) { c0r[i] = 0.f; c1r[i] = 0.f; }

    __syncthreads();

#pragma unroll 1
    for (int t = 0; t < kT; ++t) {
      const int p = t & 1;
      const ushort* h0rd = h0b[p ^ 1];
      ushort* h0wr = h0b[p];
      const ushort* h1rd = h1b[p ^ 1];
      ushort* h1wr = h1b[p];

      // ---------------- layer 0: z0' = scaled(b0 + x*w0) + h0_{t-1} @ W ----
      f32x4 acc[2][4];
#pragma unroll
      for (int mt = 0; mt < 2; ++mt)
#pragma unroll
        for (int r = 0; r < 4; ++r) {
          float xv = xsf[(16 * mt + 4 * grp + r) * 17 + t];
#pragma unroll
          for (int j = 0; j < 4; ++j) acc[mt][j][r] = fmaf(xv, w0g[j], b0g[j]);
        }
#pragma unroll
      for (int ks = 0; ks < 2; ++ks) {
        short8 a0 = ldA(h0rd, 0, 32 * ks);
        short8 a1 = ldA(h0rd, 1, 32 * ks);
#pragma unroll
        for (int j = 0; j < 4; ++j) {
          acc[0][j] = __builtin_amdgcn_mfma_f32_16x16x32_bf16(a0, bL0[ks * 4 + j], acc[0][j], 0, 0, 0);
          acc[1][j] = __builtin_amdgcn_mfma_f32_16x16x32_bf16(a1, bL0[ks * 4 + j], acc[1][j], 0, 0, 0);
        }
      }
      // gates L0 -> h0wr (no barrier: h0wr is the parity buffer nobody reads
      // this t; L0 readers used h0rd)
#pragma unroll
      for (int mt = 0; mt < 2; ++mt)
#pragma unroll
        for (int r = 0; r < 4; ++r) {
          int row = 16 * mt + 4 * grp + r;
          float ig = __builtin_amdgcn_rcpf(1.f + exp2x(acc[mt][0][r]));
          float fg = __builtin_amdgcn_rcpf(1.f + exp2x(acc[mt][1][r]));
          float gg = 1.f - 2.f * __builtin_amdgcn_rcpf(1.f + exp2x(acc[mt][2][r]));
          float og = __builtin_amdgcn_rcpf(1.f + exp2x(acc[mt][3][r]));
          float c = fmaf(fg, c0r[mt * 4 + r], ig * gg);
          c0r[mt * 4 + r] = c;
          float th = 1.f - 2.f * __builtin_amdgcn_rcpf(1.f + exp2x(c * 2.88539008177792681472f));
          h0wr[row * 64 + (u ^ ((row & 7) << 3))] = f2bf_fast(og * th);
        }
      __syncthreads();  // the ONE barrier: h0_t visible for L1 (and orders
                        // all cross-parity hazards per the race audit)

      // ---------------- layer 1: z1' = scaled(b1) + [h0_t; h1_{t-1}] @ W ----
#pragma unroll
      for (int mt = 0; mt < 2; ++mt)
#pragma unroll
        for (int j = 0; j < 4; ++j)
#pragma unroll
          for (int r = 0; r < 4; ++r) acc[mt][j][r] = b1g[j];
#pragma unroll
      for (int ks = 0; ks < 2; ++ks) {
        short8 a0 = ldA(h0wr, 0, 32 * ks);
        short8 a1 = ldA(h0wr, 1, 32 * ks);
#pragma unroll
        for (int j = 0; j < 4; ++j) {
          acc[0][j] = __builtin_amdgcn_mfma_f32_16x16x32_bf16(a0, bL1[ks * 4 + j], acc[0][j], 0, 0, 0);
          acc[1][j] = __builtin_amdgcn_mfma_f32_16x16x32_bf16(a1, bL1[ks * 4 + j], acc[1][j], 0, 0, 0);
        }
      }
#pragma unroll
      for (int ks = 2; ks < 4; ++ks) {
        short8 a0 = ldA(h1rd, 0, 32 * (ks - 2));
        short8 a1 = ldA(h1rd, 1, 32 * (ks - 2));
#pragma unroll
        for (int j = 0; j < 4; ++j) {
          acc[0][j] = __builtin_amdgcn_mfma_f32_16x16x32_bf16(a0, bL1[ks * 4 + j], acc[0][j], 0, 0, 0);
          acc[1][j] = __builtin_amdgcn_mfma_f32_16x16x32_bf16(a1, bL1[ks * 4 + j], acc[1][j], 0, 0, 0);
        }
      }
      // gates L1 -> h1wr (no barrier: h1wr is the unread parity buffer;
      // next-t orderings come from the t+1 barrier)
#pragma unroll
      for (int mt = 0; mt < 2; ++mt)
#pragma unroll
        for (int r = 0; r < 4; ++r) {
          int row = 16 * mt + 4 * grp + r;
          float ig = __builtin_amdgcn_rcpf(1.f + exp2x(acc[mt][0][r]));
          float fg = __builtin_amdgcn_rcpf(1.f + exp2x(acc[mt][1][r]));
          float gg = 1.f - 2.f * __builtin_amdgcn_rcpf(1.f + exp2x(acc[mt][2][r]));
          float og = __builtin_amdgcn_rcpf(1.f + exp2x(acc[mt][3][r]));
          float c = fmaf(fg, c1r[mt * 4 + r], ig * gg);
          c1r[mt * 4 + r] = c;
          float th = 1.f - 2.f * __builtin_amdgcn_rcpf(1.f + exp2x(c * 2.88539008177792681472f));
          float h = og * th;
          if (t < kT - 1) {
            h1wr[row * 64 + (u ^ ((row & 7) << 3))] = f2bf_fast(h);
          } else {
            h1f[row * 68 + u] = h;
          }
        }
    }
    __syncthreads();  // h1f visible for FC (also drains last L1-mfma reads)

    // ---------------- FC + exact-erf GELU (fp32) ----------------
    {
      const int o = tid & 63;
      const int ms = tid >> 6;
      float yv[8];
      float fb = fc_b[o];
#pragma unroll
      for (int i = 0; i < 8; ++i) yv[i] = fb;
#pragma unroll 1
      for (int u0 = 0; u0 < 64; u0 += 4) {
        float q0 = ws[WS_FCT + (u0 + 0) * 64 + o];
        float q1 = ws[WS_FCT + (u0 + 1) * 64 + o];
        float q2 = ws[WS_FCT + (u0 + 2) * 64 + o];
        float q3 = ws[WS_FCT + (u0 + 3) * 64 + o];
#pragma unroll
        for (int i = 0; i < 8; ++i) {
          const float4 hq = *(const float4*)&h1f[(ms * 8 + i) * 68 + u0];
          yv[i] = fmaf(hq.x, q0, yv[i]);
          yv[i] = fmaf(hq.y, q1, yv[i]);
          yv[i] = fmaf(hq.z, q2, yv[i]);
          yv[i] = fmaf(hq.w, q3, yv[i]);
        }
      }
#pragma unroll
      for (int i = 0; i < 8; ++i) {
        float v = yv[i];
        float g = 0.5f * v * (1.f + erff(v * 0.70710678118654752f));
        out[(size_t)(bm0 + ms * 8 + i) * 64 + o] = g;
      }
    }
    // no barrier: next tile's staging (h0b[1]/h1b[1]/xsf) is disjoint from
    // h1f/out, and all h-buffer reads ended before the post-loop barrier.
  }
}

extern "C" void kernel_launch(void* const* d_in, const int* in_sizes, int n_in,
                              void* d_out, int out_size, void* d_ws, size_t ws_size,
                              hipStream_t stream) {
  const float* x = (const float*)d_in[0];
  const float* bn_gamma = (const float*)d_in[1];
  const float* bn_beta = (const float*)d_in[2];
  const float* w_ih0 = (const float*)d_in[3];
  const float* w_hh0 = (const float*)d_in[4];
  const float* b_ih0 = (const float*)d_in[5];
  const float* b_hh0 = (const float*)d_in[6];
  const float* w_ih1 = (const float*)d_in[7];
  const float* w_hh1 = (const float*)d_in[8];
  const float* b_ih1 = (const float*)d_in[9];
  const float* b_hh1 = (const float*)d_in[10];
  const float* fc_w = (const float*)d_in[11];
  const float* fc_b = (const float*)d_in[12];
  float* ws = (float*)d_ws;
  float* out = (float*)d_out;

  hipLaunchKernelGGL(prep_kernel, dim3(64), dim3(256), 0, stream,
                     w_hh0, w_ih1, w_hh1, b_ih0, b_hh0, b_ih1, b_hh1, fc_w, ws);
  hipLaunchKernelGGL(bn_sums_kernel, dim3(256), dim3(256), 0, stream, x, ws);
  hipLaunchKernelGGL(bn_final_kernel, dim3(1), dim3(64), 0, stream,
                     bn_gamma, bn_beta, ws);
  hipLaunchKernelGGL(lstm_fused_kernel, dim3(kGrid), dim3(256), 0, stream,
                     x, w_ih0, fc_b, ws, out);
}